// Round 13
// baseline (293.038 us; speedup 1.0000x reference)
//
#include <hip/hip_runtime.h>
#include <hip/hip_bf16.h>

// Problem constants
#define NSEQ 4096
#define C4   1024
#define SCALE_F 0.17677669529663687f   // (256/8)^-0.5
#define SLC   524288                   // floats per partial slice: 16*128*256

typedef __attribute__((ext_vector_type(8))) short bf16x8;
typedef __attribute__((ext_vector_type(4))) float f32x4;
typedef __attribute__((ext_vector_type(8))) unsigned short u16x8;
typedef __attribute__((ext_vector_type(4))) unsigned short u16x4;

__device__ __forceinline__ float b2f(unsigned short b){
  union{unsigned u; float f;} v; v.u = ((unsigned)b)<<16; return v.f;
}
__device__ __forceinline__ unsigned short f2b(float x){
  union{float f; unsigned u;} v; v.f = x;
  unsigned r = v.u + 0x7fffu + ((v.u>>16)&1u);
  return (unsigned short)(r>>16);
}
// monotone f32 <-> u32 mapping for atomicMax pooling
__device__ __forceinline__ unsigned mapf(float x){
  unsigned u = __float_as_uint(x);
  return (u & 0x80000000u) ? ~u : (u | 0x80000000u);
}
__device__ __forceinline__ float unmapf(unsigned m){
  unsigned u = (m & 0x80000000u) ? (m ^ 0x80000000u) : ~m;
  return __uint_as_float(u);
}

typedef __attribute__((address_space(1))) void* gas_p;
typedef __attribute__((address_space(3))) void* las_p;
#define GLDS16(gp, lp) __builtin_amdgcn_global_load_lds((gas_p)(gp), (las_p)(lp), 16, 0, 0)

#define WAITVM8() asm volatile("s_waitcnt vmcnt(8)" ::: "memory")
#define WAITVM4() asm volatile("s_waitcnt vmcnt(4)" ::: "memory")
#define WAITVM0() asm volatile("s_waitcnt vmcnt(0)" ::: "memory")
#define WAITLGKM() asm volatile("s_waitcnt lgkmcnt(0)" ::: "memory")
__device__ __forceinline__ void barrier(){
  asm volatile("" ::: "memory");
  __builtin_amdgcn_s_barrier();
  asm volatile("" ::: "memory");
}

// Stage a 128x64 bf16 tile, chunk-XOR swizzled: LDS slot (r,c8) holds global chunk (c8^(r&7)).
__device__ __forceinline__ void stage128x64s(const unsigned short* G, int row0, int ld, int k0,
                                             unsigned short* lds, int tid){
#pragma unroll
  for (int i = 0; i < 4; ++i){
    int cid = i*256 + tid;          // 1024 chunks of 16B
    int r = cid >> 3, c8 = cid & 7;
    GLDS16(G + (row0 + r)*ld + k0 + ((c8 ^ (r & 7))*8), lds + cid*8);
  }
}

// Stage a 128x128 bf16 tile, chunk-XOR swizzled (same read formula, LD=128).
__device__ __forceinline__ void stage128x128s(const unsigned short* G, int row0, int ld, int k0,
                                              unsigned short* lds, int tid){
#pragma unroll
  for (int i = 0; i < 8; ++i){
    int cid = i*256 + tid;          // 2048 chunks of 16B
    int r = cid >> 4, c16 = cid & 15;
    GLDS16(G + (row0 + r)*ld + k0 + ((c16 ^ (r & 7))*8), lds + cid*8);
  }
}

// Read element (row, c) from a 4-panel chunk-swizzled [128][256] tile (stage128x64s x4).
__device__ __forceinline__ float gtread(const unsigned short* gtile, int row, int c){
  int p = c >> 6, cc = c & 63, c8g = cc >> 3, j = cc & 7;
  return b2f(gtile[p*8192 + row*64 + ((c8g ^ (row & 7)) << 3) + j]);
}

// MFMA over staged tiles. D[m,n] += sum_k A[m,k]*B[n,k].
// Modes: 0=linear, 1=chunk-XOR (stage*s), 2=np-XOR (reg-transposed B).
template<int LD, int NK, int MA, int MB>
__device__ __forceinline__ void mma_tiles(const unsigned short* ldsA, const unsigned short* ldsB,
                                          f32x4 acc[4][4], int wr, int wc, int lane){
  const int rowg = lane & 15, q4 = lane >> 4;
#pragma unroll
  for (int kc = 0; kc < NK; ++kc){
    bf16x8 a[4], b[4];
#pragma unroll
    for (int mf = 0; mf < 4; ++mf){
      int row = wr*64 + mf*16 + rowg;
      int off;
      if constexpr (MA == 1) off = ((kc*4 + q4) ^ (row & 7)) * 8;
      else                   off = kc*32 + q4*8;
      a[mf] = *(const bf16x8*)(ldsA + row*LD + off);
    }
#pragma unroll
    for (int nf = 0; nf < 4; ++nf){
      int col = wc*64 + nf*16 + rowg;
      int off;
      if constexpr (MB == 1)      off = ((kc*4 + q4) ^ (col & 7)) * 8;
      else if constexpr (MB == 2) off = (kc*32 + q4*8) ^ ((((col>>3) ^ col) & 7) << 3);
      else                        off = kc*32 + q4*8;
      b[nf] = *(const bf16x8*)(ldsB + col*LD + off);
    }
#pragma unroll
    for (int mf = 0; mf < 4; ++mf)
#pragma unroll
      for (int nf = 0; nf < 4; ++nf)
        acc[mf][nf] = __builtin_amdgcn_mfma_f32_16x16x32_bf16(a[mf], b[nf], acc[mf][nf], 0, 0, 0);
  }
}

// ---------------- x cast + pooled zero-fill (fused) ----------------
__global__ __launch_bounds__(256) void k_cast(const float* __restrict__ src,
                                              unsigned short* __restrict__ dst,
                                              unsigned* __restrict__ pooled, int n){
  int i = (blockIdx.x*256 + threadIdx.x) * 4;
  if (i < n){
    float4 v = *(const float4*)(src + i);
    u16x4 o = { f2b(v.x), f2b(v.y), f2b(v.z), f2b(v.w) };
    *(u16x4*)(dst + i) = o;
  }
  if (blockIdx.x < 2048){
    uint4 z = {0u, 0u, 0u, 0u};
    *(uint4*)(pooled + (blockIdx.x*256 + threadIdx.x)*4) = z;
  }
}

// ---------------- fused weight prep: casts + transposes, grid (256, 6) ----------------
__global__ __launch_bounds__(256) void k_wprep(const float* __restrict__ Wq, const float* __restrict__ Wk,
                                               const float* __restrict__ Wv, const float* __restrict__ Wp,
                                               unsigned short* __restrict__ Wcat,
                                               unsigned short* __restrict__ Wpbf,
                                               unsigned short* __restrict__ WcatT,
                                               unsigned short* __restrict__ WvT){
  int t = blockIdx.x*256 + threadIdx.x;
  int s = blockIdx.y;
  if (s < 3){
    const float* src = (s == 0) ? Wq : (s == 1) ? Wk : Wp;
    unsigned short* dst = (s == 0) ? Wcat : (s == 1) ? (Wcat + 262144) : Wpbf;
    int i = t*4;
    float4 v = *(const float4*)(src + i);
    u16x4 o = { f2b(v.x), f2b(v.y), f2b(v.z), f2b(v.w) };
    *(u16x4*)(dst + i) = o;
  } else {
    const float* src = (s == 3) ? Wv : (s == 4) ? Wq : Wk;
    unsigned short* dst = (s == 3) ? WvT : WcatT;
    int ld  = (s == 3) ? 1024 : 2048;
    int off = (s == 5) ? 1024 : 0;
    int j = t & 255, r0 = (t >> 8) * 4;
    u16x4 o = { f2b(src[(r0+0)*256 + j]), f2b(src[(r0+1)*256 + j]),
                f2b(src[(r0+2)*256 + j]), f2b(src[(r0+3)*256 + j]) };
    *(u16x4*)(dst + j*ld + off + r0) = o;
  }
}

// ---------------- Gram[s][c][c'] = sum_c4 W_s[c4,c]*W_s[c4,c'], grid (2,2,2) ----------------
__global__ __launch_bounds__(256) void k_gram(const unsigned short* __restrict__ WcatT,
                                              unsigned short* __restrict__ Gram){
  __shared__ __align__(16) unsigned short ldsA[128*64];
  __shared__ __align__(16) unsigned short ldsB[128*64];
  int tid = threadIdx.x, lane = tid & 63, wid = tid >> 6, wr = wid >> 1, wc = wid & 1;
  int m0 = blockIdx.x*128, n0 = blockIdx.y*128, off = blockIdx.z*1024;
  f32x4 acc[4][4] = {};
  for (int k0 = 0; k0 < 1024; k0 += 64){
    __syncthreads();
    stage128x64s(WcatT, m0, 2048, off + k0, ldsA, tid);
    stage128x64s(WcatT, n0, 2048, off + k0, ldsB, tid);
    __syncthreads();
    mma_tiles<64,2,1,1>(ldsA, ldsB, acc, wr, wc, lane);
  }
  int colg = lane & 15, rowg = (lane >> 4) * 4;
#pragma unroll
  for (int mf = 0; mf < 4; ++mf)
#pragma unroll
    for (int nf = 0; nf < 4; ++nf)
#pragma unroll
      for (int r = 0; r < 4; ++r)
        Gram[blockIdx.z*65536 + (m0 + wr*64 + mf*16 + rowg + r)*256 + n0 + wc*64 + nf*16 + colg]
          = f2b(acc[mf][nf][r]);
}

// ---------------- q/k projection + fused adaptive-max-pool (NO X store) ----------------
__global__ __launch_bounds__(256) void k_gemm_qk(const unsigned short* __restrict__ xbf,
                                                 const unsigned short* __restrict__ Wcat,
                                                 unsigned* __restrict__ pooled){
  __shared__ __align__(16) unsigned short ldsA[128*64];
  __shared__ __align__(16) unsigned short ldsB[128*64];
  int tid = threadIdx.x, lane = tid & 63, wid = tid >> 6, wr = wid >> 1, wc = wid & 1;
  int m0 = blockIdx.x*128, n0 = blockIdx.y*128;
  f32x4 acc[4][4] = {};
  for (int k0 = 0; k0 < 256; k0 += 64){
    __syncthreads();
    stage128x64s(xbf,  m0, 256, k0, ldsA, tid);
    stage128x64s(Wcat, n0, 256, k0, ldsB, tid);
    __syncthreads();
    mma_tiles<64,2,1,1>(ldsA, ldsB, acc, wr, wc, lane);
  }
  int colg = lane & 15;
  int b = m0 >> 12, kbase = (m0 & 4095) >> 5;
#pragma unroll
  for (int nf = 0; nf < 4; ++nf){
    float wlo = -3e38f, whi = -3e38f;
#pragma unroll
    for (int r = 0; r < 4; ++r){
      wlo = fmaxf(wlo, fmaxf(acc[0][nf][r], acc[1][nf][r]));
      whi = fmaxf(whi, fmaxf(acc[2][nf][r], acc[3][nf][r]));
    }
    wlo = fmaxf(wlo, __shfl_xor(wlo, 16)); wlo = fmaxf(wlo, __shfl_xor(wlo, 32));
    whi = fmaxf(whi, __shfl_xor(whi, 16)); whi = fmaxf(whi, __shfl_xor(whi, 32));
    if (lane < 16){
      int col = n0 + wc*64 + nf*16 + colg;
      int sbp = b + ((col >> 10) << 3);
      int c4 = col & 1023;
      atomicMax(&pooled[(sbp*128 + kbase + wr*2    )*C4 + c4], mapf(wlo));
      atomicMax(&pooled[(sbp*128 + kbase + wr*2 + 1)*C4 + c4], mapf(whi));
    }
  }
}

// ---------------- l2-normalize rows over c4 -> basesT bf16 ----------------
__global__ __launch_bounds__(256) void k_norm(const float* __restrict__ bRaw,
                                              const unsigned* __restrict__ pooled,
                                              unsigned short* __restrict__ basesT, int S){
  int row = blockIdx.x, tid = threadIdx.x, lane = tid & 63, wid = tid >> 6;
  float4 v;
  if (S == 0){
    uint4 u = *(const uint4*)(pooled + row*C4 + tid*4);
    v.x = unmapf(u.x); v.y = unmapf(u.y); v.z = unmapf(u.z); v.w = unmapf(u.w);
  } else {
    v = *(const float4*)(bRaw + row*C4 + tid*4);
  }
  float ss = v.x*v.x + v.y*v.y + v.z*v.z + v.w*v.w;
  __shared__ float red[5];
#pragma unroll
  for (int o = 32; o; o >>= 1) ss += __shfl_down(ss, o);
  if (lane == 0) red[wid] = ss;
  __syncthreads();
  if (tid == 0) red[4] = 1.f / (1e-6f + sqrtf(red[0] + red[1] + red[2] + red[3]));
  __syncthreads();
  float inv = red[4];
  u16x4 o4 = { f2b(v.x*inv), f2b(v.y*inv), f2b(v.z*inv), f2b(v.w*inv) };
  *(u16x4*)(basesT + row*C4 + tid*4) = o4;
}

// ---------------- PB partial: part[ks][sb][k][c] = sum_{c4 in ks} basesT[sb][k][c4]*WcatT[c][off+c4] ----------------
__global__ __launch_bounds__(256) void k_pb(const unsigned short* __restrict__ basesT,
                                            const unsigned short* __restrict__ WcatT,
                                            float* __restrict__ part){
  __shared__ __align__(16) unsigned short ldsA[128*64];
  __shared__ __align__(16) unsigned short ldsB[128*64];
  int tid = threadIdx.x, lane = tid & 63, wid = tid >> 6, wr = wid >> 1, wc = wid & 1;
  int n0 = blockIdx.x*128, sb = blockIdx.y, ks = blockIdx.z;
  const unsigned short* A = basesT + sb*(128*C4);
  int off = (sb >= 8) ? 1024 : 0;
  f32x4 acc[4][4] = {};
  for (int t = 0; t < 4; ++t){
    __syncthreads();
    stage128x64s(A,     0,  C4,   ks*256 + t*64, ldsA, tid);
    stage128x64s(WcatT, n0, 2048, off + ks*256 + t*64, ldsB, tid);
    __syncthreads();
    mma_tiles<64,2,1,1>(ldsA, ldsB, acc, wr, wc, lane);
  }
  int colg = lane & 15, rowg = (lane >> 4) * 4;
#pragma unroll
  for (int mf = 0; mf < 4; ++mf)
#pragma unroll
    for (int nf = 0; nf < 4; ++nf)
#pragma unroll
      for (int r = 0; r < 4; ++r)
        part[ks*SLC + (sb*128 + wr*64 + mf*16 + rowg + r)*256 + n0 + wc*64 + nf*16 + colg]
          = acc[mf][nf][r];
}

// ---------------- reduce S partial slices -> bf16 ----------------
__global__ __launch_bounds__(256) void k_redgt(const float* __restrict__ src,
                                               unsigned short* __restrict__ dst, int S){
  int i = (blockIdx.x*256 + threadIdx.x) * 4;   // over SLC
  float4 a = {0.f,0.f,0.f,0.f};
  for (int s = 0; s < S; ++s){
    float4 u = *(const float4*)(src + s*SLC + i);
    a.x += u.x; a.y += u.y; a.z += u.z; a.w += u.w;
  }
  u16x4 o = { f2b(a.x), f2b(a.y), f2b(a.z), f2b(a.w) };
  *(u16x4*)(dst + i) = o;
}

// ---------------- normPB: PBT[sb][k][c] = (GT.Gram)[k][c] / (1e-6 + ||W.GT[k]||), grid (16) ----------------
// ||W.GT[k]||^2 = sum_c (GT.Gram)[k][c] * GT[k][c]  (Gram = W^T W, symmetric)
__global__ __launch_bounds__(256) void k_normpb(const unsigned short* __restrict__ GTbf,
                                                const unsigned short* __restrict__ Gram,
                                                unsigned short* __restrict__ PBT){
  __shared__ __align__(16) unsigned short gtile[128*256];   // 64KB, 4 chunk-swz panels
  __shared__ __align__(16) unsigned short btile[128*64];    // 16KB
  __shared__ float redn[2][128];
  int tid = threadIdx.x, lane = tid & 63, wid = tid >> 6, wr = wid >> 1, wc = wid & 1;
  int sb = blockIdx.x;
  const unsigned short* GTsb = GTbf + sb*(128*256);
  const unsigned short* Gm = Gram + ((sb >= 8) ? 65536 : 0);
#pragma unroll
  for (int p = 0; p < 4; ++p)
    stage128x64s(GTsb, 0, 256, p*64, gtile + p*8192, tid);
  f32x4 accA[4][4] = {}, accB[4][4] = {};
  for (int t = 0; t < 4; ++t){
    __syncthreads();
    stage128x64s(Gm, 0, 256, t*64, btile, tid);
    __syncthreads();
    mma_tiles<64,2,1,1>(gtile + t*8192, btile, accA, wr, wc, lane);
  }
  for (int t = 0; t < 4; ++t){
    __syncthreads();
    stage128x64s(Gm, 128, 256, t*64, btile, tid);
    __syncthreads();
    mma_tiles<64,2,1,1>(gtile + t*8192, btile, accB, wr, wc, lane);
  }
  int colg = lane & 15, rowg = (lane >> 4) * 4;
#pragma unroll
  for (int mf = 0; mf < 4; ++mf)
#pragma unroll
    for (int r = 0; r < 4; ++r){
      int row = wr*64 + mf*16 + rowg + r;
      float d = 0.f;
#pragma unroll
      for (int nf = 0; nf < 4; ++nf){
        int cA = wc*64 + nf*16 + colg;
        d += accA[mf][nf][r] * gtread(gtile, row, cA);
        d += accB[mf][nf][r] * gtread(gtile, row, 128 + cA);
      }
#pragma unroll
      for (int o = 1; o < 16; o <<= 1) d += __shfl_xor(d, o);
      if (colg == 0) redn[wc][row] = d;
    }
  __syncthreads();
#pragma unroll
  for (int mf = 0; mf < 4; ++mf)
#pragma unroll
    for (int r = 0; r < 4; ++r){
      int row = wr*64 + mf*16 + rowg + r;
      float nrm2 = fmaxf(redn[0][row] + redn[1][row], 0.f);
      float inv = 1.f / (1e-6f + sqrtf(nrm2));
#pragma unroll
      for (int nf = 0; nf < 4; ++nf){
        int cA = wc*64 + nf*16 + colg;
        PBT[(sb*128 + row)*256 + cA]       = f2b(accA[mf][nf][r] * inv);
        PBT[(sb*128 + row)*256 + 128 + cA] = f2b(accB[mf][nf][r] * inv);
      }
    }
}

// ---------------- z-step: scores[n,k] = x[n,:].PBT[k,:] (K=256); softmax over k; store zT[k][n] ----------------
__global__ __launch_bounds__(256) void k_gemm_z(const unsigned short* __restrict__ xbf,
                                                const unsigned short* __restrict__ PBT,
                                                unsigned short* __restrict__ zT){
  __shared__ __align__(16) unsigned short smem[32768];
  __shared__ float redb[2][2][128];
  unsigned short* zt = smem;
  int tid = threadIdx.x, lane = tid & 63, wid = tid >> 6, wr = wid >> 1, wc = wid & 1;
  int m0 = blockIdx.x*128, sb = blockIdx.y;
  const unsigned short* A = xbf + (sb & 7)*(NSEQ*256);
  const unsigned short* B = PBT + sb*(128*256);
  f32x4 acc[4][4] = {};
  stage128x64s(A, m0, 256, 0, smem, tid);
  stage128x64s(B, 0,  256, 0, smem + 16384, tid);
  for (int t = 0; t < 4; ++t){
    int cur = t & 1;
    if (t < 3){
      stage128x64s(A, m0, 256, (t+1)*64, smem + (cur^1)*8192, tid);
      stage128x64s(B, 0,  256, (t+1)*64, smem + 16384 + (cur^1)*8192, tid);
      WAITVM8();
    } else WAITVM0();
    barrier();
    mma_tiles<64,2,1,1>(smem + cur*8192, smem + 16384 + cur*8192, acc, wr, wc, lane);
    WAITLGKM();
    barrier();
  }
  int colg = lane & 15, rowg = (lane >> 4) * 4;
  float sm[4][4];
#pragma unroll
  for (int mf = 0; mf < 4; ++mf)
#pragma unroll
    for (int r = 0; r < 4; ++r){
      float m = fmaxf(fmaxf(acc[mf][0][r], acc[mf][1][r]), fmaxf(acc[mf][2][r], acc[mf][3][r]));
#pragma unroll
      for (int o = 1; o < 16; o <<= 1) m = fmaxf(m, __shfl_xor(m, o));
      if (colg == 0) redb[0][wc][wr*64 + mf*16 + rowg + r] = m;
    }
  barrier();
#pragma unroll
  for (int mf = 0; mf < 4; ++mf)
#pragma unroll
    for (int r = 0; r < 4; ++r){
      int idx = wr*64 + mf*16 + rowg + r;
      float m = fmaxf(redb[0][0][idx], redb[0][1][idx]);
      float s = 0.f;
#pragma unroll
      for (int nf = 0; nf < 4; ++nf){
        float e = __expf(acc[mf][nf][r] - m);
        acc[mf][nf][r] = e; s += e;
      }
#pragma unroll
      for (int o = 1; o < 16; o <<= 1) s += __shfl_xor(s, o);
      if (colg == 0) redb[1][wc][idx] = s;
    }
  barrier();
#pragma unroll
  for (int mf = 0; mf < 4; ++mf)
#pragma unroll
    for (int r = 0; r < 4; ++r){
      int idx = wr*64 + mf*16 + rowg + r;
      sm[mf][r] = 1.f / (redb[1][0][idx] + redb[1][1][idx]);
    }
#pragma unroll
  for (int mf = 0; mf < 4; ++mf)
#pragma unroll
    for (int nf = 0; nf < 4; ++nf){
      int k = wc*64 + nf*16 + colg;
      int swz = (k & 7) << 3;
#pragma unroll
      for (int r = 0; r < 4; ++r){
        int n = wr*64 + mf*16 + rowg + r;
        zt[k*128 + (n ^ swz)] = f2b(acc[mf][nf][r] * sm[mf][r]);
      }
    }
  WAITLGKM();
  barrier();
#pragma unroll
  for (int i = 0; i < 8; ++i){
    int cid = i*256 + tid;
    int kk = cid >> 4, j8 = cid & 15;
    int nbase = (j8*8) ^ ((kk & 7) << 3);
    *(uint4*)(zT + sb*(128*NSEQ) + kk*NSEQ + m0 + nbase) = *(const uint4*)(zt + kk*128 + j8*8);
  }
}

// ---------------- GT partial: part[ks][sb][k][c] = sum_{n in ks} zT[k,n]*x[n,c] ----------------
__global__ __launch_bounds__(256) void k_gemm_gt(const unsigned short* __restrict__ xbf,
                                                 const unsigned short* __restrict__ zT,
                                                 float* __restrict__ part){
  __shared__ __align__(16) unsigned short ldsA[2][8192];
  __shared__ __align__(16) unsigned short ldsB[2][8192];   // x^T: [128 c][64 n], np-XOR swizzled
  int tid = threadIdx.x, lane = tid & 63, wid = tid >> 6, wr = wid >> 1, wc = wid & 1;
  int c0 = blockIdx.x*128, sb = blockIdx.y, ks = blockIdx.z;
  const unsigned short* xb = xbf + (sb & 7)*(NSEQ*256);
  const unsigned short* Zt = zT + sb*(128*NSEQ);
  int base = ks*512;
  f32x4 acc[4][4] = {};
  u16x8 vB[4];
  int np_[4], c8_[4];
#pragma unroll
  for (int i = 0; i < 4; ++i){
    int cid = i*256 + tid;
    np_[i] = cid >> 4; c8_[i] = cid & 15;
  }
  stage128x64s(Zt, 0, NSEQ, base, ldsA[0], tid);
#pragma unroll
  for (int i = 0; i < 4; ++i)
    vB[i] = *(const u16x8*)(xb + (base + np_[i])*256 + c0 + c8_[i]*8);
  for (int t = 0; t < 8; ++t){
    int cur = t & 1, n0 = base + t*64;
    if (t < 7){
      stage128x64s(Zt, 0, NSEQ, n0 + 64, ldsA[cur^1], tid);
      WAITVM4();
    } else WAITVM0();
#pragma unroll
    for (int i = 0; i < 4; ++i){
#pragma unroll
      for (int j = 0; j < 8; ++j)
        ldsB[cur][(c8_[i]*8 + j)*64 + (np_[i] ^ (((c8_[i] ^ j) & 7) << 3))] = vB[i][j];
    }
    WAITLGKM();
    barrier();
    if (t < 7){
#pragma unroll
      for (int i = 0; i < 4; ++i)
        vB[i] = *(const u16x8*)(xb + (n0 + 64 + np_[i])*256 + c0 + c8_[i]*8);
    }
    mma_tiles<64,2,1,2>(ldsA[cur], ldsB[cur], acc, wr, wc, lane);
    WAITLGKM();
    barrier();
  }
  int colg = lane & 15, rowg = (lane >> 4) * 4;
#pragma unroll
  for (int mf = 0; mf < 4; ++mf)
#pragma unroll
    for (int nf = 0; nf < 4; ++nf)
#pragma unroll
      for (int r = 0; r < 4; ++r)
        part[ks*SLC + (sb*128 + wr*64 + mf*16 + rowg + r)*256 + c0 + wc*64 + nf*16 + colg]
          = acc[mf][nf][r];
}

// ---------------- bases_new raw: bRaw[sb][k][c4] = sum_c W[c4,c]*GT[k,c] ----------------
__global__ __launch_bounds__(256) void k_pbases(const unsigned short* __restrict__ Wcat,
                                                const unsigned short* __restrict__ GTbf,
                                                float* __restrict__ bRaw){
  __shared__ __align__(16) unsigned short ldsA[128*64];
  __shared__ __align__(16) unsigned short ldsB[128*64];
  int tid = threadIdx.x, lane = tid & 63, wid = tid >> 6, wr = wid >> 1, wc = wid & 1;
  int m0 = blockIdx.x*128, sb = blockIdx.y;
  const unsigned short* A = Wcat + ((sb >= 8) ? 1024*256 : 0);
  const unsigned short* B = GTbf + sb*(128*256);
  f32x4 acc[4][4] = {};
  for (int t = 0; t < 4; ++t){
    __syncthreads();
    stage128x64s(A, m0, 256, t*64, ldsA, tid);
    stage128x64s(B, 0,  256, t*64, ldsB, tid);
    __syncthreads();
    mma_tiles<64,2,1,1>(ldsA, ldsB, acc, wr, wc, lane);
  }
  int colg = lane & 15, rowg = (lane >> 4) * 4;
#pragma unroll
  for (int mf = 0; mf < 4; ++mf)
#pragma unroll
    for (int nf = 0; nf < 4; ++nf)
#pragma unroll
      for (int r = 0; r < 4; ++r){
        int c4 = m0 + wr*64 + mf*16 + rowg + r;
        int k  = wc*64 + nf*16 + colg;
        bRaw[(sb*128 + k)*C4 + c4] = acc[mf][nf][r];
      }
}

// ---------------- fused attn + wpeff, grid (2, 64) ----------------
__global__ __launch_bounds__(256) void k_attnwp(const unsigned short* __restrict__ basesT,
                                                const unsigned short* __restrict__ Wpbf,
                                                unsigned short* __restrict__ WpEff){
  __shared__ __align__(16) char smem[98816];
  unsigned short* Qlt = (unsigned short*)smem;             // [128 d][128 k]
  unsigned short* Klt = (unsigned short*)(smem + 32768);   // [128 e][128 k]
  float* scores       = (float*)smem;                      // [128][129], aliases operands (post-MMA)
  unsigned short* at  = (unsigned short*)(smem + 66048);   // [128 e][128 d]
  unsigned short* Wl  = (unsigned short*)smem;             // [128 c][128 d], phase B (aliases scores)
  int tid = threadIdx.x, lane = tid & 63, wid = tid >> 6, wr = wid >> 1, wc = wid & 1;
  int m0 = blockIdx.x*128;
  int bh = blockIdx.y, b = bh >> 3, h = bh & 7;
  const unsigned short* Q = basesT + b*(128*C4) + h*128;
  const unsigned short* K = basesT + (8 + b)*(128*C4) + h*128;
#pragma unroll
  for (int i = 0; i < 8; ++i){
    int cid = i*256 + tid, kk = cid >> 4, c8 = cid & 15;
    u16x8 vq = *(const u16x8*)(Q + kk*C4 + c8*8);
    u16x8 vk = *(const u16x8*)(K + kk*C4 + c8*8);
#pragma unroll
    for (int j = 0; j < 8; ++j){
      Qlt[(c8*8 + j)*128 + kk] = vq[j];
      Klt[(c8*8 + j)*128 + kk] = vk[j];
    }
  }
  __syncthreads();
  f32x4 acc[4][4] = {};
  mma_tiles<128,4,0,0>(Qlt, Klt, acc, wr, wc, lane);
  __syncthreads();
  int colg = lane & 15, rowg = (lane >> 4) * 4;
#pragma unroll
  for (int mf = 0; mf < 4; ++mf)
#pragma unroll
    for (int nf = 0; nf < 4; ++nf)
#pragma unroll
      for (int r = 0; r < 4; ++r)
        scores[(wr*64 + mf*16 + rowg + r)*129 + wc*64 + nf*16 + colg] = acc[mf][nf][r] * SCALE_F;
  __syncthreads();
  if (tid < 128){
    float mx = -3e38f;
    for (int j = 0; j < 128; ++j) mx = fmaxf(mx, scores[tid*129 + j]);
    float s = 0.f;
    for (int j = 0; j < 128; ++j){ float e = __expf(scores[tid*129 + j] - mx); scores[tid*129 + j] = e; s += e; }
    float inv = 1.f / s;
    for (int j = 0; j < 128; ++j) at[j*128 + tid] = f2b(scores[tid*129 + j] * inv);
  }
  __syncthreads();
  stage128x128s(Wpbf, m0, C4, h*128, Wl, tid);
  __syncthreads();
  f32x4 acc2[4][4] = {};
  mma_tiles<128,4,1,0>(Wl, at, acc2, wr, wc, lane);
#pragma unroll
  for (int mf = 0; mf < 4; ++mf)
#pragma unroll
    for (int nf = 0; nf < 4; ++nf)
#pragma unroll
      for (int r = 0; r < 4; ++r){
        int row = m0 + wr*64 + mf*16 + rowg + r;
        int col = wc*64 + nf*16 + colg;
        WpEff[b*(256*C4) + row*C4 + h*128 + col] = f2b(acc2[mf][nf][r]);
      }
}

// ---------------- W2[b][c][j] = sum_c4 WpEff[b][c][c4] * WvT[j][c4] ----------------
__global__ __launch_bounds__(256) void k_gemm_w2(const unsigned short* __restrict__ WpEff,
                                                 const unsigned short* __restrict__ WvT,
                                                 unsigned short* __restrict__ W2){
  __shared__ __align__(16) unsigned short ldsA[128*64];
  __shared__ __align__(16) unsigned short ldsB[128*64];
  int tid = threadIdx.x, lane = tid & 63, wid = tid >> 6, wr = wid >> 1, wc = wid & 1;
  int m0 = blockIdx.x*128, n0 = blockIdx.y*128, b = blockIdx.z;
  const unsigned short* A = WpEff + b*(256*C4);
  f32x4 acc[4][4] = {};
  for (int k0 = 0; k0 < C4; k0 += 64){
    __syncthreads();
    stage128x64s(A,   m0, C4, k0, ldsA, tid);
    stage128x64s(WvT, n0, C4, k0, ldsB, tid);
    __syncthreads();
    mma_tiles<64,2,1,1>(ldsA, ldsB, acc, wr, wc, lane);
  }
  int colg = lane & 15, rowg = (lane >> 4) * 4;
#pragma unroll
  for (int mf = 0; mf < 4; ++mf)
#pragma unroll
    for (int nf = 0; nf < 4; ++nf)
#pragma unroll
      for (int r = 0; r < 4; ++r){
        int row = m0 + wr*64 + mf*16 + rowg + r;
        int col = n0 + wc*64 + nf*16 + colg;
        W2[b*65536 + row*256 + col] = f2b(acc[mf][nf][r]);
      }
}

// ---------------- out[b,n,c] = relu( sum_j x[b,n,j]*W2[b][c][j] + bp[c] ) ----------------
__global__ __launch_bounds__(256) void k_gemm_out(const unsigned short* __restrict__ xbf,
                                                  const unsigned short* __restrict__ W2,
                                                  const float* __restrict__ bp,
                                                  float* __restrict__ out){
  __shared__ __align__(16) unsigned short ldsA[2][8192];
  __shared__ __align__(16) unsigned short ldsB[2][8192];
  int tid = threadIdx.x, lane = tid & 63, wid = tid >> 6, wr = wid >> 1, wc = wid & 1;
  int m0 = blockIdx.x*128, n0 = blockIdx.y*128, b = blockIdx.z;
  const unsigned short* A = xbf + b*(NSEQ*256);
  const unsigned short* Bm = W2 + b*65536;
  f32x4 acc[4][4] = {};
  stage128x64s(A,  m0, 256, 0, ldsA[0], tid);
  stage128x64s(Bm, n0, 256, 0, ldsB[0], tid);
  for (int t = 0; t < 4; ++t){
    int cur = t & 1;
    if (t < 3){
      stage128x64s(A,  m0, 256, (t+1)*64, ldsA[cur^1], tid);
      stage128x64s(Bm, n0, 256, (t+1)*64, ldsB[cur^1], tid);
      WAITVM8();
    } else WAITVM0();
    barrier();
    mma_tiles<64,2,1,1>(ldsA[cur], ldsB[cur], acc, wr, wc, lane);
    WAITLGKM();
    barrier();
  }
  int colg = lane & 15, rowg = (lane >> 4) * 4;
#pragma unroll
  for (int mf = 0; mf < 4; ++mf)
#pragma unroll
    for (int nf = 0; nf < 4; ++nf){
      int col = n0 + wc*64 + nf*16 + colg;
      float bias = bp[col];
#pragma unroll
      for (int r = 0; r < 4; ++r){
        int row = m0 + wr*64 + mf*16 + rowg + r;
        out[(b*NSEQ + row)*256 + col] = fmaxf(acc[mf][nf][r] + bias, 0.f);
      }
    }
}

extern "C" void kernel_launch(void* const* d_in, const int* in_sizes, int n_in,
                              void* d_out, int out_size, void* d_ws, size_t ws_size,
                              hipStream_t stream){
  (void)in_sizes; (void)n_in; (void)out_size; (void)ws_size;
  const float* x  = (const float*)d_in[0];
  const float* Wq = (const float*)d_in[1];
  const float* Wk = (const float*)d_in[2];
  const float* Wv = (const float*)d_in[3];
  const float* Wp = (const float*)d_in[4];
  const float* bp = (const float*)d_in[5];
  float* out = (float*)d_out;
  char* ws = (char*)d_ws;

  unsigned short* xbf    = (unsigned short*)(ws + 0);          // 16 MB [8][4096][256] bf16
  unsigned short* zT     = (unsigned short*)(ws + 16777216);   // 16 MB [16][128][4096] bf16
  float*          bPart  = (float*)(ws + 33554432);            // 16 MB [8][16][128][256] f32
  unsigned*       pooled = (unsigned*)(ws + 50331648);         // 8 MB  [16][128][1024] u32
  float*          bRawP  = (float*)(ws + 58720256);            // 8 MB  [16][128][1024] f32
  unsigned short* basesT = (unsigned short*)(ws + 67108864);   // 4 MB  [16][128][1024] bf16
  unsigned short* WpEff  = (unsigned short*)(ws + 71303168);   // 4 MB  [8][256][1024] bf16
  unsigned short* PBT    = (unsigned short*)(ws + 77594624);   // 1 MB  [16][128][256] bf16
  unsigned short* GTbf   = (unsigned short*)(ws + 78643200);   // 1 MB  [16][128][256] bf16
  unsigned short* Wcat   = (unsigned short*)(ws + 79691776);   // 1 MB  [2048][256] bf16 (Wq;Wk)
  unsigned short* WcatT  = (unsigned short*)(ws + 80740352);   // 1 MB  [256][2048] bf16 (WqT|WkT)
  unsigned short* W2     = (unsigned short*)(ws + 81788928);   // 1 MB  [8][256][256] bf16
  unsigned short* WvT    = (unsigned short*)(ws + 82837504);   // 0.5MB [256][1024] bf16
  unsigned short* Wpbf   = (unsigned short*)(ws + 83361792);   // 0.5MB [256][1024] bf16
  unsigned short* Gram   = (unsigned short*)(ws + 83886080);   // 256KB [2][256][256] bf16

  k_cast<<<8192, 256, 0, stream>>>(x, xbf, pooled, 8388608);
  k_wprep<<<dim3(256, 6), 256, 0, stream>>>(Wq, Wk, Wv, Wp, Wcat, Wpbf, WcatT, WvT);
  k_gram<<<dim3(2, 2, 2), 256, 0, stream>>>(WcatT, Gram);

  k_gemm_qk<<<dim3(256, 16), 256, 0, stream>>>(xbf, Wcat, pooled);
  k_norm<<<2048, 256, 0, stream>>>(bRawP, pooled, basesT, 0);

  // stage 0: PB from pooled bases (c4-space)
  k_pb<<<dim3(2, 16, 4), 256, 0, stream>>>(basesT, WcatT, bPart);
  k_redgt<<<512, 256, 0, stream>>>(bPart, PBT, 4);
  k_gemm_z<<<dim3(32, 16), 256, 0, stream>>>(xbf, PBT, zT);
  k_gemm_gt<<<dim3(2, 16, 8), 256, 0, stream>>>(xbf, zT, bPart);
  k_redgt<<<512, 256, 0, stream>>>(bPart, GTbf, 8);

  // stages 1..2: PB directly from GT via Gram (c-space only)
  for (int st = 1; st < 3; ++st){
    k_normpb<<<16, 256, 0, stream>>>(GTbf, Gram, PBT);
    k_gemm_z<<<dim3(32, 16), 256, 0, stream>>>(xbf, PBT, zT);
    k_gemm_gt<<<dim3(2, 16, 8), 256, 0, stream>>>(xbf, zT, bPart);
    k_redgt<<<512, 256, 0, stream>>>(bPart, GTbf, 8);
  }

  // final bases for attention
  k_pbases<<<dim3(8, 16), 256, 0, stream>>>(Wcat, GTbf, bRawP);
  k_norm<<<2048, 256, 0, stream>>>(bRawP, pooled, basesT, 1);

  k_attnwp<<<dim3(2, 64), 256, 0, stream>>>(basesT, Wpbf, WpEff);
  k_gemm_w2<<<dim3(2, 2, 8), 256, 0, stream>>>(WpEff, WvT, W2);
  k_gemm_out<<<dim3(32, 2, 8), 256, 0, stream>>>(xbf, W2, bp, out);
}

// Round 14
// 287.873 us; speedup vs baseline: 1.0179x; 1.0179x over previous
//
#include <hip/hip_runtime.h>
#include <hip/hip_bf16.h>

// Problem constants
#define NSEQ 4096
#define C4   1024
#define SCALE_F 0.17677669529663687f   // (256/8)^-0.5
#define SLC   524288                   // floats per partial slice: 16*128*256

typedef __attribute__((ext_vector_type(8))) short bf16x8;
typedef __attribute__((ext_vector_type(4))) float f32x4;
typedef __attribute__((ext_vector_type(8))) unsigned short u16x8;
typedef __attribute__((ext_vector_type(4))) unsigned short u16x4;

__device__ __forceinline__ unsigned short f2b(float x){
  union{float f; unsigned u;} v; v.f = x;
  unsigned r = v.u + 0x7fffu + ((v.u>>16)&1u);
  return (unsigned short)(r>>16);
}
// monotone f32 <-> u32 mapping for atomicMax pooling
__device__ __forceinline__ unsigned mapf(float x){
  unsigned u = __float_as_uint(x);
  return (u & 0x80000000u) ? ~u : (u | 0x80000000u);
}
__device__ __forceinline__ float unmapf(unsigned m){
  unsigned u = (m & 0x80000000u) ? (m ^ 0x80000000u) : ~m;
  return __uint_as_float(u);
}

typedef __attribute__((address_space(1))) void* gas_p;
typedef __attribute__((address_space(3))) void* las_p;
#define GLDS16(gp, lp) __builtin_amdgcn_global_load_lds((gas_p)(gp), (las_p)(lp), 16, 0, 0)

#define WAITVM8() asm volatile("s_waitcnt vmcnt(8)" ::: "memory")
#define WAITVM4() asm volatile("s_waitcnt vmcnt(4)" ::: "memory")
#define WAITVM0() asm volatile("s_waitcnt vmcnt(0)" ::: "memory")
#define WAITLGKM() asm volatile("s_waitcnt lgkmcnt(0)" ::: "memory")
__device__ __forceinline__ void barrier(){
  asm volatile("" ::: "memory");
  __builtin_amdgcn_s_barrier();
  asm volatile("" ::: "memory");
}

// Stage a 128x64 bf16 tile, chunk-XOR swizzled: LDS slot (r,c8) holds global chunk (c8^(r&7)).
__device__ __forceinline__ void stage128x64s(const unsigned short* G, int row0, int ld, int k0,
                                             unsigned short* lds, int tid){
#pragma unroll
  for (int i = 0; i < 4; ++i){
    int cid = i*256 + tid;          // 1024 chunks of 16B
    int r = cid >> 3, c8 = cid & 7;
    GLDS16(G + (row0 + r)*ld + k0 + ((c8 ^ (r & 7))*8), lds + cid*8);
  }
}

// Stage a 128x128 bf16 tile, chunk-XOR swizzled (same read formula, LD=128).
__device__ __forceinline__ void stage128x128s(const unsigned short* G, int row0, int ld, int k0,
                                              unsigned short* lds, int tid){
#pragma unroll
  for (int i = 0; i < 8; ++i){
    int cid = i*256 + tid;          // 2048 chunks of 16B
    int r = cid >> 4, c16 = cid & 15;
    GLDS16(G + (row0 + r)*ld + k0 + ((c16 ^ (r & 7))*8), lds + cid*8);
  }
}

// MFMA over staged tiles. D[m,n] += sum_k A[m,k]*B[n,k].
// Modes: 0=linear, 1=chunk-XOR (stage*s), 2=np-XOR (reg-transposed B).
template<int LD, int NK, int MA, int MB>
__device__ __forceinline__ void mma_tiles(const unsigned short* ldsA, const unsigned short* ldsB,
                                          f32x4 acc[4][4], int wr, int wc, int lane){
  const int rowg = lane & 15, q4 = lane >> 4;
#pragma unroll
  for (int kc = 0; kc < NK; ++kc){
    bf16x8 a[4], b[4];
#pragma unroll
    for (int mf = 0; mf < 4; ++mf){
      int row = wr*64 + mf*16 + rowg;
      int off;
      if constexpr (MA == 1) off = ((kc*4 + q4) ^ (row & 7)) * 8;
      else                   off = kc*32 + q4*8;
      a[mf] = *(const bf16x8*)(ldsA + row*LD + off);
    }
#pragma unroll
    for (int nf = 0; nf < 4; ++nf){
      int col = wc*64 + nf*16 + rowg;
      int off;
      if constexpr (MB == 1)      off = ((kc*4 + q4) ^ (col & 7)) * 8;
      else if constexpr (MB == 2) off = (kc*32 + q4*8) ^ ((((col>>3) ^ col) & 7) << 3);
      else                        off = kc*32 + q4*8;
      b[nf] = *(const bf16x8*)(ldsB + col*LD + off);
    }
#pragma unroll
    for (int mf = 0; mf < 4; ++mf)
#pragma unroll
      for (int nf = 0; nf < 4; ++nf)
        acc[mf][nf] = __builtin_amdgcn_mfma_f32_16x16x32_bf16(a[mf], b[nf], acc[mf][nf], 0, 0, 0);
  }
}

// ---------------- x cast + pooled zero-fill (fused) ----------------
__global__ __launch_bounds__(256) void k_cast(const float* __restrict__ src,
                                              unsigned short* __restrict__ dst,
                                              unsigned* __restrict__ pooled, int n){
  int i = (blockIdx.x*256 + threadIdx.x) * 4;
  if (i < n){
    float4 v = *(const float4*)(src + i);
    u16x4 o = { f2b(v.x), f2b(v.y), f2b(v.z), f2b(v.w) };
    *(u16x4*)(dst + i) = o;
  }
  if (blockIdx.x < 2048){
    uint4 z = {0u, 0u, 0u, 0u};
    *(uint4*)(pooled + (blockIdx.x*256 + threadIdx.x)*4) = z;
  }
}

// ---------------- fused weight prep: casts + transposes, grid (256, 6) ----------------
__global__ __launch_bounds__(256) void k_wprep(const float* __restrict__ Wq, const float* __restrict__ Wk,
                                               const float* __restrict__ Wv, const float* __restrict__ Wp,
                                               unsigned short* __restrict__ Wcat,
                                               unsigned short* __restrict__ Wpbf,
                                               unsigned short* __restrict__ WcatT,
                                               unsigned short* __restrict__ WvT){
  int t = blockIdx.x*256 + threadIdx.x;
  int s = blockIdx.y;
  if (s < 3){
    const float* src = (s == 0) ? Wq : (s == 1) ? Wk : Wp;
    unsigned short* dst = (s == 0) ? Wcat : (s == 1) ? (Wcat + 262144) : Wpbf;
    int i = t*4;
    float4 v = *(const float4*)(src + i);
    u16x4 o = { f2b(v.x), f2b(v.y), f2b(v.z), f2b(v.w) };
    *(u16x4*)(dst + i) = o;
  } else {
    const float* src = (s == 3) ? Wv : (s == 4) ? Wq : Wk;
    unsigned short* dst = (s == 3) ? WvT : WcatT;
    int ld  = (s == 3) ? 1024 : 2048;
    int off = (s == 5) ? 1024 : 0;
    int j = t & 255, r0 = (t >> 8) * 4;
    u16x4 o = { f2b(src[(r0+0)*256 + j]), f2b(src[(r0+1)*256 + j]),
                f2b(src[(r0+2)*256 + j]), f2b(src[(r0+3)*256 + j]) };
    *(u16x4*)(dst + j*ld + off + r0) = o;
  }
}

// ---------------- q/k projection + fused adaptive-max-pool (NO X store) ----------------
__global__ __launch_bounds__(256) void k_gemm_qk(const unsigned short* __restrict__ xbf,
                                                 const unsigned short* __restrict__ Wcat,
                                                 unsigned* __restrict__ pooled){
  __shared__ __align__(16) unsigned short ldsA[128*64];
  __shared__ __align__(16) unsigned short ldsB[128*64];
  int tid = threadIdx.x, lane = tid & 63, wid = tid >> 6, wr = wid >> 1, wc = wid & 1;
  int m0 = blockIdx.x*128, n0 = blockIdx.y*128;
  f32x4 acc[4][4] = {};
  for (int k0 = 0; k0 < 256; k0 += 64){
    __syncthreads();
    stage128x64s(xbf,  m0, 256, k0, ldsA, tid);
    stage128x64s(Wcat, n0, 256, k0, ldsB, tid);
    __syncthreads();
    mma_tiles<64,2,1,1>(ldsA, ldsB, acc, wr, wc, lane);
  }
  int colg = lane & 15;
  int b = m0 >> 12, kbase = (m0 & 4095) >> 5;
#pragma unroll
  for (int nf = 0; nf < 4; ++nf){
    float wlo = -3e38f, whi = -3e38f;
#pragma unroll
    for (int r = 0; r < 4; ++r){
      wlo = fmaxf(wlo, fmaxf(acc[0][nf][r], acc[1][nf][r]));
      whi = fmaxf(whi, fmaxf(acc[2][nf][r], acc[3][nf][r]));
    }
    wlo = fmaxf(wlo, __shfl_xor(wlo, 16)); wlo = fmaxf(wlo, __shfl_xor(wlo, 32));
    whi = fmaxf(whi, __shfl_xor(whi, 16)); whi = fmaxf(whi, __shfl_xor(whi, 32));
    if (lane < 16){
      int col = n0 + wc*64 + nf*16 + colg;
      int sbp = b + ((col >> 10) << 3);
      int c4 = col & 1023;
      atomicMax(&pooled[(sbp*128 + kbase + wr*2    )*C4 + c4], mapf(wlo));
      atomicMax(&pooled[(sbp*128 + kbase + wr*2 + 1)*C4 + c4], mapf(whi));
    }
  }
}

// ---------------- l2-normalize rows over c4 -> basesT bf16 ----------------
__global__ __launch_bounds__(256) void k_norm(const float* __restrict__ bRaw,
                                              const unsigned* __restrict__ pooled,
                                              unsigned short* __restrict__ basesT, int S){
  int row = blockIdx.x, tid = threadIdx.x, lane = tid & 63, wid = tid >> 6;
  float4 v;
  if (S == 0){
    uint4 u = *(const uint4*)(pooled + row*C4 + tid*4);
    v.x = unmapf(u.x); v.y = unmapf(u.y); v.z = unmapf(u.z); v.w = unmapf(u.w);
  } else {
    v = *(const float4*)(bRaw + row*C4 + tid*4);
  }
  float ss = v.x*v.x + v.y*v.y + v.z*v.z + v.w*v.w;
  __shared__ float red[5];
#pragma unroll
  for (int o = 32; o; o >>= 1) ss += __shfl_down(ss, o);
  if (lane == 0) red[wid] = ss;
  __syncthreads();
  if (tid == 0) red[4] = 1.f / (1e-6f + sqrtf(red[0] + red[1] + red[2] + red[3]));
  __syncthreads();
  float inv = red[4];
  u16x4 o4 = { f2b(v.x*inv), f2b(v.y*inv), f2b(v.z*inv), f2b(v.w*inv) };
  *(u16x4*)(basesT + row*C4 + tid*4) = o4;
}

// ---------------- PB partial: part[ks][sb][k][c] = sum_{c4 in ks} basesT[sb][k][c4]*WcatT[c][off+c4] ----------------
__global__ __launch_bounds__(256) void k_pb(const unsigned short* __restrict__ basesT,
                                            const unsigned short* __restrict__ WcatT,
                                            float* __restrict__ part){
  __shared__ __align__(16) unsigned short ldsA[128*64];
  __shared__ __align__(16) unsigned short ldsB[128*64];
  int tid = threadIdx.x, lane = tid & 63, wid = tid >> 6, wr = wid >> 1, wc = wid & 1;
  int n0 = blockIdx.x*128, sb = blockIdx.y, ks = blockIdx.z;
  const unsigned short* A = basesT + sb*(128*C4);
  int off = (sb >= 8) ? 1024 : 0;
  f32x4 acc[4][4] = {};
  for (int t = 0; t < 4; ++t){
    __syncthreads();
    stage128x64s(A,     0,  C4,   ks*256 + t*64, ldsA, tid);
    stage128x64s(WcatT, n0, 2048, off + ks*256 + t*64, ldsB, tid);
    __syncthreads();
    mma_tiles<64,2,1,1>(ldsA, ldsB, acc, wr, wc, lane);
  }
  int colg = lane & 15, rowg = (lane >> 4) * 4;
#pragma unroll
  for (int mf = 0; mf < 4; ++mf)
#pragma unroll
    for (int nf = 0; nf < 4; ++nf)
#pragma unroll
      for (int r = 0; r < 4; ++r)
        part[ks*SLC + (sb*128 + wr*64 + mf*16 + rowg + r)*256 + n0 + wc*64 + nf*16 + colg]
          = acc[mf][nf][r];
}

// ---------------- reduce S partial slices -> bf16 ----------------
__global__ __launch_bounds__(256) void k_redgt(const float* __restrict__ src,
                                               unsigned short* __restrict__ dst, int S){
  int i = (blockIdx.x*256 + threadIdx.x) * 4;   // over SLC
  float4 a = {0.f,0.f,0.f,0.f};
  for (int s = 0; s < S; ++s){
    float4 u = *(const float4*)(src + s*SLC + i);
    a.x += u.x; a.y += u.y; a.z += u.z; a.w += u.w;
  }
  u16x4 o = { f2b(a.x), f2b(a.y), f2b(a.z), f2b(a.w) };
  *(u16x4*)(dst + i) = o;
}

// ---------------- z-step: scores[n,k] = x[n,:].PBT[k,:] (K=256); softmax over k; store zT[k][n] ----------------
__global__ __launch_bounds__(256) void k_gemm_z(const unsigned short* __restrict__ xbf,
                                                const unsigned short* __restrict__ PBT,
                                                unsigned short* __restrict__ zT){
  __shared__ __align__(16) unsigned short smem[32768];
  __shared__ float redb[2][2][128];
  unsigned short* zt = smem;
  int tid = threadIdx.x, lane = tid & 63, wid = tid >> 6, wr = wid >> 1, wc = wid & 1;
  int m0 = blockIdx.x*128, sb = blockIdx.y;
  const unsigned short* A = xbf + (sb & 7)*(NSEQ*256);
  const unsigned short* B = PBT + sb*(128*256);
  f32x4 acc[4][4] = {};
  stage128x64s(A, m0, 256, 0, smem, tid);
  stage128x64s(B, 0,  256, 0, smem + 16384, tid);
  for (int t = 0; t < 4; ++t){
    int cur = t & 1;
    if (t < 3){
      stage128x64s(A, m0, 256, (t+1)*64, smem + (cur^1)*8192, tid);
      stage128x64s(B, 0,  256, (t+1)*64, smem + 16384 + (cur^1)*8192, tid);
      WAITVM8();
    } else WAITVM0();
    barrier();
    mma_tiles<64,2,1,1>(smem + cur*8192, smem + 16384 + cur*8192, acc, wr, wc, lane);
    WAITLGKM();
    barrier();
  }
  int colg = lane & 15, rowg = (lane >> 4) * 4;
  float sm[4][4];
#pragma unroll
  for (int mf = 0; mf < 4; ++mf)
#pragma unroll
    for (int r = 0; r < 4; ++r){
      float m = fmaxf(fmaxf(acc[mf][0][r], acc[mf][1][r]), fmaxf(acc[mf][2][r], acc[mf][3][r]));
#pragma unroll
      for (int o = 1; o < 16; o <<= 1) m = fmaxf(m, __shfl_xor(m, o));
      if (colg == 0) redb[0][wc][wr*64 + mf*16 + rowg + r] = m;
    }
  barrier();
#pragma unroll
  for (int mf = 0; mf < 4; ++mf)
#pragma unroll
    for (int r = 0; r < 4; ++r){
      int idx = wr*64 + mf*16 + rowg + r;
      float m = fmaxf(redb[0][0][idx], redb[0][1][idx]);
      float s = 0.f;
#pragma unroll
      for (int nf = 0; nf < 4; ++nf){
        float e = __expf(acc[mf][nf][r] - m);
        acc[mf][nf][r] = e; s += e;
      }
#pragma unroll
      for (int o = 1; o < 16; o <<= 1) s += __shfl_xor(s, o);
      if (colg == 0) redb[1][wc][idx] = s;
    }
  barrier();
#pragma unroll
  for (int mf = 0; mf < 4; ++mf)
#pragma unroll
    for (int r = 0; r < 4; ++r){
      int idx = wr*64 + mf*16 + rowg + r;
      sm[mf][r] = 1.f / (redb[1][0][idx] + redb[1][1][idx]);
    }
#pragma unroll
  for (int mf = 0; mf < 4; ++mf)
#pragma unroll
    for (int nf = 0; nf < 4; ++nf){
      int k = wc*64 + nf*16 + colg;
      int swz = (k & 7) << 3;
#pragma unroll
      for (int r = 0; r < 4; ++r){
        int n = wr*64 + mf*16 + rowg + r;
        zt[k*128 + (n ^ swz)] = f2b(acc[mf][nf][r] * sm[mf][r]);
      }
    }
  WAITLGKM();
  barrier();
#pragma unroll
  for (int i = 0; i < 8; ++i){
    int cid = i*256 + tid;
    int kk = cid >> 4, j8 = cid & 15;
    int nbase = (j8*8) ^ ((kk & 7) << 3);
    *(uint4*)(zT + sb*(128*NSEQ) + kk*NSEQ + m0 + nbase) = *(const uint4*)(zt + kk*128 + j8*8);
  }
}

// ---------------- GT partial: part[ks][sb][k][c] = sum_{n in ks} zT[k,n]*x[n,c] ----------------
__global__ __launch_bounds__(256) void k_gemm_gt(const unsigned short* __restrict__ xbf,
                                                 const unsigned short* __restrict__ zT,
                                                 float* __restrict__ part){
  __shared__ __align__(16) unsigned short ldsA[2][8192];
  __shared__ __align__(16) unsigned short ldsB[2][8192];   // x^T: [128 c][64 n], np-XOR swizzled
  int tid = threadIdx.x, lane = tid & 63, wid = tid >> 6, wr = wid >> 1, wc = wid & 1;
  int c0 = blockIdx.x*128, sb = blockIdx.y, ks = blockIdx.z;
  const unsigned short* xb = xbf + (sb & 7)*(NSEQ*256);
  const unsigned short* Zt = zT + sb*(128*NSEQ);
  int base = ks*512;
  f32x4 acc[4][4] = {};
  u16x8 vB[4];
  int np_[4], c8_[4];
#pragma unroll
  for (int i = 0; i < 4; ++i){
    int cid = i*256 + tid;
    np_[i] = cid >> 4; c8_[i] = cid & 15;
  }
  stage128x64s(Zt, 0, NSEQ, base, ldsA[0], tid);
#pragma unroll
  for (int i = 0; i < 4; ++i)
    vB[i] = *(const u16x8*)(xb + (base + np_[i])*256 + c0 + c8_[i]*8);
  for (int t = 0; t < 8; ++t){
    int cur = t & 1, n0 = base + t*64;
    if (t < 7){
      stage128x64s(Zt, 0, NSEQ, n0 + 64, ldsA[cur^1], tid);
      WAITVM4();
    } else WAITVM0();
#pragma unroll
    for (int i = 0; i < 4; ++i){
#pragma unroll
      for (int j = 0; j < 8; ++j)
        ldsB[cur][(c8_[i]*8 + j)*64 + (np_[i] ^ (((c8_[i] ^ j) & 7) << 3))] = vB[i][j];
    }
    WAITLGKM();
    barrier();
    if (t < 7){
#pragma unroll
      for (int i = 0; i < 4; ++i)
        vB[i] = *(const u16x8*)(xb + (n0 + 64 + np_[i])*256 + c0 + c8_[i]*8);
    }
    mma_tiles<64,2,1,2>(ldsA[cur], ldsB[cur], acc, wr, wc, lane);
    WAITLGKM();
    barrier();
  }
  int colg = lane & 15, rowg = (lane >> 4) * 4;
#pragma unroll
  for (int mf = 0; mf < 4; ++mf)
#pragma unroll
    for (int nf = 0; nf < 4; ++nf)
#pragma unroll
      for (int r = 0; r < 4; ++r)
        part[ks*SLC + (sb*128 + wr*64 + mf*16 + rowg + r)*256 + c0 + wc*64 + nf*16 + colg]
          = acc[mf][nf][r];
}

// ---------------- bases_new raw: bRaw[sb][k][c4] = sum_c W[c4,c]*GT[k,c] ----------------
__global__ __launch_bounds__(256) void k_pbases(const unsigned short* __restrict__ Wcat,
                                                const unsigned short* __restrict__ GTbf,
                                                float* __restrict__ bRaw){
  __shared__ __align__(16) unsigned short ldsA[128*64];
  __shared__ __align__(16) unsigned short ldsB[128*64];
  int tid = threadIdx.x, lane = tid & 63, wid = tid >> 6, wr = wid >> 1, wc = wid & 1;
  int m0 = blockIdx.x*128, sb = blockIdx.y;
  const unsigned short* A = Wcat + ((sb >= 8) ? 1024*256 : 0);
  const unsigned short* B = GTbf + sb*(128*256);
  f32x4 acc[4][4] = {};
  for (int t = 0; t < 4; ++t){
    __syncthreads();
    stage128x64s(A, m0, 256, t*64, ldsA, tid);
    stage128x64s(B, 0,  256, t*64, ldsB, tid);
    __syncthreads();
    mma_tiles<64,2,1,1>(ldsA, ldsB, acc, wr, wc, lane);
  }
  int colg = lane & 15, rowg = (lane >> 4) * 4;
#pragma unroll
  for (int mf = 0; mf < 4; ++mf)
#pragma unroll
    for (int nf = 0; nf < 4; ++nf)
#pragma unroll
      for (int r = 0; r < 4; ++r){
        int c4 = m0 + wr*64 + mf*16 + rowg + r;
        int k  = wc*64 + nf*16 + colg;
        bRaw[(sb*128 + k)*C4 + c4] = acc[mf][nf][r];
      }
}

// ---------------- fused attn + wpeff, grid (2, 64) ----------------
__global__ __launch_bounds__(256) void k_attnwp(const unsigned short* __restrict__ basesT,
                                                const unsigned short* __restrict__ Wpbf,
                                                unsigned short* __restrict__ WpEff){
  __shared__ __align__(16) char smem[98816];
  unsigned short* Qlt = (unsigned short*)smem;             // [128 d][128 k]
  unsigned short* Klt = (unsigned short*)(smem + 32768);   // [128 e][128 k]
  float* scores       = (float*)smem;                      // [128][129], aliases operands (post-MMA)
  unsigned short* at  = (unsigned short*)(smem + 66048);   // [128 e][128 d]
  unsigned short* Wl  = (unsigned short*)smem;             // [128 c][128 d], phase B (aliases scores)
  int tid = threadIdx.x, lane = tid & 63, wid = tid >> 6, wr = wid >> 1, wc = wid & 1;
  int m0 = blockIdx.x*128;
  int bh = blockIdx.y, b = bh >> 3, h = bh & 7;
  const unsigned short* Q = basesT + b*(128*C4) + h*128;
  const unsigned short* K = basesT + (8 + b)*(128*C4) + h*128;
#pragma unroll
  for (int i = 0; i < 8; ++i){
    int cid = i*256 + tid, kk = cid >> 4, c8 = cid & 15;
    u16x8 vq = *(const u16x8*)(Q + kk*C4 + c8*8);
    u16x8 vk = *(const u16x8*)(K + kk*C4 + c8*8);
#pragma unroll
    for (int j = 0; j < 8; ++j){
      Qlt[(c8*8 + j)*128 + kk] = vq[j];
      Klt[(c8*8 + j)*128 + kk] = vk[j];
    }
  }
  __syncthreads();
  f32x4 acc[4][4] = {};
  mma_tiles<128,4,0,0>(Qlt, Klt, acc, wr, wc, lane);
  __syncthreads();
  int colg = lane & 15, rowg = (lane >> 4) * 4;
#pragma unroll
  for (int mf = 0; mf < 4; ++mf)
#pragma unroll
    for (int nf = 0; nf < 4; ++nf)
#pragma unroll
      for (int r = 0; r < 4; ++r)
        scores[(wr*64 + mf*16 + rowg + r)*129 + wc*64 + nf*16 + colg] = acc[mf][nf][r] * SCALE_F;
  __syncthreads();
  if (tid < 128){
    float mx = -3e38f;
    for (int j = 0; j < 128; ++j) mx = fmaxf(mx, scores[tid*129 + j]);
    float s = 0.f;
    for (int j = 0; j < 128; ++j){ float e = __expf(scores[tid*129 + j] - mx); scores[tid*129 + j] = e; s += e; }
    float inv = 1.f / s;
    for (int j = 0; j < 128; ++j) at[j*128 + tid] = f2b(scores[tid*129 + j] * inv);
  }
  __syncthreads();
  stage128x128s(Wpbf, m0, C4, h*128, Wl, tid);
  __syncthreads();
  f32x4 acc2[4][4] = {};
  mma_tiles<128,4,1,0>(Wl, at, acc2, wr, wc, lane);
#pragma unroll
  for (int mf = 0; mf < 4; ++mf)
#pragma unroll
    for (int nf = 0; nf < 4; ++nf)
#pragma unroll
      for (int r = 0; r < 4; ++r){
        int row = m0 + wr*64 + mf*16 + rowg + r;
        int col = wc*64 + nf*16 + colg;
        WpEff[b*(256*C4) + row*C4 + h*128 + col] = f2b(acc2[mf][nf][r]);
      }
}

// ---------------- W2[b][c][j] = sum_c4 WpEff[b][c][c4] * WvT[j][c4] ----------------
__global__ __launch_bounds__(256) void k_gemm_w2(const unsigned short* __restrict__ WpEff,
                                                 const unsigned short* __restrict__ WvT,
                                                 unsigned short* __restrict__ W2){
  __shared__ __align__(16) unsigned short ldsA[128*64];
  __shared__ __align__(16) unsigned short ldsB[128*64];
  int tid = threadIdx.x, lane = tid & 63, wid = tid >> 6, wr = wid >> 1, wc = wid & 1;
  int m0 = blockIdx.x*128, n0 = blockIdx.y*128, b = blockIdx.z;
  const unsigned short* A = WpEff + b*(256*C4);
  f32x4 acc[4][4] = {};
  for (int k0 = 0; k0 < C4; k0 += 64){
    __syncthreads();
    stage128x64s(A,   m0, C4, k0, ldsA, tid);
    stage128x64s(WvT, n0, C4, k0, ldsB, tid);
    __syncthreads();
    mma_tiles<64,2,1,1>(ldsA, ldsB, acc, wr, wc, lane);
  }
  int colg = lane & 15, rowg = (lane >> 4) * 4;
#pragma unroll
  for (int mf = 0; mf < 4; ++mf)
#pragma unroll
    for (int nf = 0; nf < 4; ++nf)
#pragma unroll
      for (int r = 0; r < 4; ++r){
        int row = m0 + wr*64 + mf*16 + rowg + r;
        int col = n0 + wc*64 + nf*16 + colg;
        W2[b*65536 + row*256 + col] = f2b(acc[mf][nf][r]);
      }
}

// ---------------- out[b,n,c] = relu( sum_j x[b,n,j]*W2[b][c][j] + bp[c] ) ----------------
__global__ __launch_bounds__(256) void k_gemm_out(const unsigned short* __restrict__ xbf,
                                                  const unsigned short* __restrict__ W2,
                                                  const float* __restrict__ bp,
                                                  float* __restrict__ out){
  __shared__ __align__(16) unsigned short ldsA[2][8192];
  __shared__ __align__(16) unsigned short ldsB[2][8192];
  int tid = threadIdx.x, lane = tid & 63, wid = tid >> 6, wr = wid >> 1, wc = wid & 1;
  int m0 = blockIdx.x*128, n0 = blockIdx.y*128, b = blockIdx.z;
  const unsigned short* A = xbf + b*(NSEQ*256);
  const unsigned short* Bm = W2 + b*65536;
  f32x4 acc[4][4] = {};
  stage128x64s(A,  m0, 256, 0, ldsA[0], tid);
  stage128x64s(Bm, n0, 256, 0, ldsB[0], tid);
  for (int t = 0; t < 4; ++t){
    int cur = t & 1;
    if (t < 3){
      stage128x64s(A,  m0, 256, (t+1)*64, ldsA[cur^1], tid);
      stage128x64s(Bm, n0, 256, (t+1)*64, ldsB[cur^1], tid);
      WAITVM8();
    } else WAITVM0();
    barrier();
    mma_tiles<64,2,1,1>(ldsA[cur], ldsB[cur], acc, wr, wc, lane);
    WAITLGKM();
    barrier();
  }
  int colg = lane & 15, rowg = (lane >> 4) * 4;
#pragma unroll
  for (int mf = 0; mf < 4; ++mf)
#pragma unroll
    for (int nf = 0; nf < 4; ++nf){
      int col = n0 + wc*64 + nf*16 + colg;
      float bias = bp[col];
#pragma unroll
      for (int r = 0; r < 4; ++r){
        int row = m0 + wr*64 + mf*16 + rowg + r;
        out[(b*NSEQ + row)*256 + col] = fmaxf(acc[mf][nf][r] + bias, 0.f);
      }
    }
}

extern "C" void kernel_launch(void* const* d_in, const int* in_sizes, int n_in,
                              void* d_out, int out_size, void* d_ws, size_t ws_size,
                              hipStream_t stream){
  (void)in_sizes; (void)n_in; (void)out_size; (void)ws_size;
  const float* x  = (const float*)d_in[0];
  const float* Wq = (const float*)d_in[1];
  const float* Wk = (const float*)d_in[2];
  const float* Wv = (const float*)d_in[3];
  const float* Wp = (const float*)d_in[4];
  const float* bp = (const float*)d_in[5];
  float* out = (float*)d_out;
  char* ws = (char*)d_ws;

  unsigned short* xbf    = (unsigned short*)(ws + 0);          // 16 MB [8][4096][256] bf16
  unsigned short* zT     = (unsigned short*)(ws + 16777216);   // 16 MB [16][128][4096] bf16
  float*          bPart  = (float*)(ws + 33554432);            // 16 MB [8][16][128][256] f32
  unsigned*       pooled = (unsigned*)(ws + 50331648);         // 8 MB  [16][128][1024] u32
  float*          bRawP  = (float*)(ws + 58720256);            // 8 MB  [16][128][1024] f32
  unsigned short* basesT = (unsigned short*)(ws + 67108864);   // 4 MB  [16][128][1024] bf16
  unsigned short* WpEff  = (unsigned short*)(ws + 71303168);   // 4 MB  [8][256][1024] bf16
  unsigned short* PBT    = (unsigned short*)(ws + 77594624);   // 1 MB  [16][128][256] bf16
  unsigned short* GTbf   = (unsigned short*)(ws + 78643200);   // 1 MB  [16][128][256] bf16
  unsigned short* Wcat   = (unsigned short*)(ws + 79691776);   // 1 MB  [2048][256] bf16 (Wq;Wk)
  unsigned short* WcatT  = (unsigned short*)(ws + 80740352);   // 1 MB  [256][2048] bf16 (WqT|WkT)
  unsigned short* W2     = (unsigned short*)(ws + 81788928);   // 1 MB  [8][256][256] bf16
  unsigned short* WvT    = (unsigned short*)(ws + 82837504);   // 0.5MB [256][1024] bf16
  unsigned short* Wpbf   = (unsigned short*)(ws + 83361792);   // 0.5MB [256][1024] bf16

  k_cast<<<8192, 256, 0, stream>>>(x, xbf, pooled, 8388608);
  k_wprep<<<dim3(256, 6), 256, 0, stream>>>(Wq, Wk, Wv, Wp, Wcat, Wpbf, WcatT, WvT);

  k_gemm_qk<<<dim3(256, 16), 256, 0, stream>>>(xbf, Wcat, pooled);
  k_norm<<<2048, 256, 0, stream>>>(bRawP, pooled, basesT, 0);

  for (int st = 0; st < 3; ++st){
    k_pb<<<dim3(2, 16, 4), 256, 0, stream>>>(basesT, WcatT, bPart);
    k_redgt<<<512, 256, 0, stream>>>(bPart, PBT, 4);
    k_gemm_z<<<dim3(32, 16), 256, 0, stream>>>(xbf, PBT, zT);
    k_gemm_gt<<<dim3(2, 16, 8), 256, 0, stream>>>(xbf, zT, bPart);
    k_redgt<<<512, 256, 0, stream>>>(bPart, GTbf, 8);
    k_pbases<<<dim3(8, 16), 256, 0, stream>>>(Wcat, GTbf, bRawP);
    k_norm<<<2048, 256, 0, stream>>>(bRawP, pooled, basesT, 1);
  }

  k_attnwp<<<dim3(2, 64), 256, 0, stream>>>(basesT, Wpbf, WpEff);
  k_gemm_w2<<<dim3(2, 2, 8), 256, 0, stream>>>(WpEff, WvT, W2);
  k_gemm_out<<<dim3(32, 2, 8), 256, 0, stream>>>(xbf, W2, bp, out);
}